// Round 2
// baseline (118.735 us; speedup 1.0000x reference)
//
#include <hip/hip_runtime.h>
#include <hip/hip_bf16.h>

// Problem constants
#define NTOK 2048
#define TOPK 2
#define HS   512
#define FFN  2048
#define NE   8
#define TASSIGN (NTOK*TOPK)   // 4096
#define PAD  5120             // 4096 + 8*128 (segments padded to 128)
#define MAXT128 40
#define MAXT64  72

typedef __attribute__((ext_vector_type(8))) short bf16x8;
typedef __attribute__((ext_vector_type(4))) float f32x4;

// ws layout (byte offsets), all 16B aligned; total ~67.2 MB
static const size_t OFF_XBF  = 0;            // [NTOK*HS] bf16
static const size_t OFF_W1T  = 2097152;      // [E][FFN][HS] bf16
static const size_t OFF_W2T  = 18874368;     // [E][HS][FFN] bf16
static const size_t OFF_H    = 35651584;     // [PAD][FFN] bf16
static const size_t OFF_OUTV = 56623104;     // [PAD][HS] f32
static const size_t OFF_RT   = 67108864;     // rowtok [PAD] int
static const size_t OFF_HROF = 67129344;     // hrof [TASSIGN] int
static const size_t OFF_TE128= 67145728;
static const size_t OFF_TR128= 67145888;
static const size_t OFF_TE64 = 67146048;
static const size_t OFF_TR64 = 67146336;

__device__ __forceinline__ unsigned short f2bf(float f) {
    union { __hip_bfloat16 h; unsigned short u; } v;
    v.h = __float2bfloat16(f);
    return v.u;
}

__device__ __forceinline__ int swz(int r, int byte_off) {
    return byte_off ^ ((r & 7) << 4);
}

#define GLOAD16(gsrc, ldst) \
    __builtin_amdgcn_global_load_lds((const __attribute__((address_space(1))) void*)(gsrc), \
                                     (__attribute__((address_space(3))) void*)(ldst), 16, 0, 0)

// ---- x fp32 -> bf16 ----
__global__ void k_xcvt(const float* __restrict__ x, unsigned short* __restrict__ xbf) {
    int i = (blockIdx.x * 256 + threadIdx.x) * 4;
    float4 v = *(const float4*)(x + i);
    ushort4 o;
    o.x = f2bf(v.x); o.y = f2bf(v.y); o.z = f2bf(v.z); o.w = f2bf(v.w);
    *(ushort4*)(xbf + i) = o;
}

// ---- transpose+convert: in [E][R][C] f32 -> out [E][C][R] bf16 ----
__global__ void k_transpose(const float* __restrict__ in, unsigned short* __restrict__ out,
                            int R, int C) {
    __shared__ unsigned short t[32][33];
    int e = blockIdx.z;
    int rb = blockIdx.y * 32, cb = blockIdx.x * 32;
    int tx = threadIdx.x, ty = threadIdx.y;
    const float* ip = in + (size_t)e * R * C;
    unsigned short* op = out + (size_t)e * C * R;
#pragma unroll
    for (int i = 0; i < 4; i++) {
        int r = ty + i * 8;
        t[r][tx] = f2bf(ip[(size_t)(rb + r) * C + cb + tx]);
    }
    __syncthreads();
#pragma unroll
    for (int i = 0; i < 4; i++) {
        int c = ty + i * 8;
        op[(size_t)(cb + c) * R + rb + tx] = t[tx][c];
    }
}

// ---- setup: counting sort by expert, 128-padded segments, two tile tables ----
__global__ void k_setup(const int* __restrict__ ei,
                        int* __restrict__ rowtok, int* __restrict__ hrof,
                        int* __restrict__ te128, int* __restrict__ tr128,
                        int* __restrict__ te64, int* __restrict__ tr64) {
    __shared__ int cnt[NE], offpad[NE], cur[NE];
    int tid = threadIdx.x;
    for (int i = tid; i < PAD; i += 256) rowtok[i] = 0;   // pad rows -> token 0 (harmless)
    if (tid < NE) cnt[tid] = 0;
    __syncthreads();
    for (int a = tid; a < TASSIGN; a += 256) atomicAdd(&cnt[ei[a]], 1);
    __syncthreads();
    if (tid == 0) {
        int o = 0, t1 = 0, t2 = 0;
        for (int e = 0; e < NE; e++) {
            offpad[e] = o; cur[e] = 0;
            for (int r = 0; r < cnt[e]; r += 128) { te128[t1] = e; tr128[t1] = o + r; t1++; }
            for (int r = 0; r < cnt[e]; r += 64)  { te64[t2]  = e; tr64[t2]  = o + r; t2++; }
            o += (cnt[e] + 127) / 128 * 128;
        }
        for (; t1 < MAXT128; t1++) te128[t1] = -1;
        for (; t2 < MAXT64;  t2++) te64[t2]  = -1;
    }
    __syncthreads();
    for (int a = tid; a < TASSIGN; a += 256) {
        int e = ei[a];
        int r = atomicAdd(&cur[e], 1);
        int hr = offpad[e] + r;
        rowtok[hr] = a >> 1;       // token = assignment / TOPK
        hrof[a] = hr;
    }
}

// ---- grouped GEMM, m97 structure: global_load_lds w=16, pre-swizzled source,
//      linear LDS dest, XOR-swizzled ds_read_b128, 2 barriers per K-step.
//      G1=true:  out = gelu(A_gathered @ B), bf16   (A rows gathered via rowtok)
//      G1=false: out = A @ B, f32                   (A rows direct)
template<int BM, int BN, int K, bool G1>
__global__ __launch_bounds__(256) void k_gemm(
        const unsigned short* __restrict__ A,
        const unsigned short* __restrict__ B,
        void* __restrict__ outp,
        const int* __restrict__ rowtok,
        const int* __restrict__ te, const int* __restrict__ tr) {
    constexpr int MI = BM / 32;      // 16x16 frags per wave, M dir
    constexpr int NJ = BN / 32;      // N dir
    constexpr int PA = BM / 32;      // global_load_lds issues per K-step (A)
    constexpr int PB = BN / 32;
    int mt = blockIdx.y;
    int e = te[mt];
    if (e < 0) return;
    int hr0 = tr[mt];
    int ct = blockIdx.x;
    int N = gridDim.x * BN;

    __shared__ unsigned short As[BM * 64];
    __shared__ unsigned short Bs[BN * 64];

    int tid = threadIdx.x;
    int lane = tid & 63, wave = tid >> 6;
    int wm = wave >> 1, wn = wave & 1;

    // per-thread pre-swizzled global source (chunk c8 of row r fetched from c8^(r&7))
    const char* asrc[PA];
    const char* bsrc[PB];
#pragma unroll
    for (int p = 0; p < PA; p++) {
        int idx = p * 256 + tid;
        int r = idx >> 3, c8 = idx & 7;
        int c8s = c8 ^ (r & 7);
        size_t row = G1 ? (size_t)rowtok[hr0 + r] : (size_t)(hr0 + r);
        asrc[p] = (const char*)(A + row * K) + c8s * 16;
    }
#pragma unroll
    for (int p = 0; p < PB; p++) {
        int idx = p * 256 + tid;
        int r = idx >> 3, c8 = idx & 7;
        int c8s = c8 ^ (r & 7);
        bsrc[p] = (const char*)(B + ((size_t)e * N + (size_t)ct * BN + r) * K) + c8s * 16;
    }
    // wave-uniform linear LDS dests (HW: base + lane*16)
    char* aldst[PA]; char* bldst[PB];
#pragma unroll
    for (int p = 0; p < PA; p++) aldst[p] = (char*)As + (p * 256 + wave * 64) * 16;
#pragma unroll
    for (int p = 0; p < PB; p++) bldst[p] = (char*)Bs + (p * 256 + wave * 64) * 16;

    f32x4 acc[MI][NJ] = {};

#pragma unroll 1
    for (int kt = 0; kt < K; kt += 64) {
#pragma unroll
        for (int p = 0; p < PA; p++) GLOAD16(asrc[p] + kt * 2, aldst[p]);
#pragma unroll
        for (int p = 0; p < PB; p++) GLOAD16(bsrc[p] + kt * 2, bldst[p]);
        __syncthreads();
#pragma unroll
        for (int kk = 0; kk < 64; kk += 32) {
            bf16x8 af[MI], bfr[NJ];
#pragma unroll
            for (int i = 0; i < MI; i++) {
                int ar = wm * (BM / 2) + i * 16 + (lane & 15);
                af[i] = *(const bf16x8*)((const char*)As + swz(ar, ar * 128 + kk * 2 + (lane >> 4) * 16));
            }
#pragma unroll
            for (int j = 0; j < NJ; j++) {
                int bc = wn * (BN / 2) + j * 16 + (lane & 15);
                bfr[j] = *(const bf16x8*)((const char*)Bs + swz(bc, bc * 128 + kk * 2 + (lane >> 4) * 16));
            }
#pragma unroll
            for (int i = 0; i < MI; i++)
#pragma unroll
                for (int j = 0; j < NJ; j++)
                    acc[i][j] = __builtin_amdgcn_mfma_f32_16x16x32_bf16(af[i], bfr[j], acc[i][j], 0, 0, 0);
        }
        __syncthreads();
    }

    if constexpr (G1) {
        unsigned short* O = (unsigned short*)outp;
#pragma unroll
        for (int i = 0; i < MI; i++)
#pragma unroll
            for (int j = 0; j < NJ; j++)
#pragma unroll
                for (int q = 0; q < 4; q++) {
                    int row = hr0 + wm * (BM / 2) + i * 16 + (lane >> 4) * 4 + q;
                    int col = ct * BN + wn * (BN / 2) + j * 16 + (lane & 15);
                    float v = acc[i][j][q];
                    float g = 0.5f * v * (1.0f + erff(v * 0.70710678118f));
                    O[(size_t)row * N + col] = f2bf(g);
                }
    } else {
        float* O = (float*)outp;
#pragma unroll
        for (int i = 0; i < MI; i++)
#pragma unroll
            for (int j = 0; j < NJ; j++)
#pragma unroll
                for (int q = 0; q < 4; q++) {
                    int row = hr0 + wm * (BM / 2) + i * 16 + (lane >> 4) * 4 + q;
                    int col = ct * BN + wn * (BN / 2) + j * 16 + (lane & 15);
                    O[(size_t)row * N + col] = acc[i][j][q];
                }
    }
}

// ---- combine: y[t] = w0*o0 + w1*o1 ; buffer[t][0..7] fully written (zeros incl.) ----
__global__ void k_combine(const float* __restrict__ outv, const int* __restrict__ ei,
                          const float* __restrict__ ew, const int* __restrict__ hrof,
                          float* __restrict__ y, float* __restrict__ buf) {
    int g = blockIdx.x * 256 + threadIdx.x;   // over NTOK*HS
    int t = g >> 9, col = g & (HS - 1);
    int a0 = 2 * t, a1 = a0 + 1;
    int h0 = hrof[a0], h1 = hrof[a1];
    float o0 = outv[(size_t)h0 * HS + col];
    float o1 = outv[(size_t)h1 * HS + col];
    y[g] = ew[a0] * o0 + ew[a1] * o1;
    int e0 = ei[a0], e1 = ei[a1];
    float* bt = buf + (size_t)t * (NE * HS) + col;
#pragma unroll
    for (int e = 0; e < NE; e++) {
        float v = (e == e0 ? o0 : 0.0f) + (e == e1 ? o1 : 0.0f);
        bt[(size_t)e * HS] = v;
    }
}

extern "C" void kernel_launch(void* const* d_in, const int* in_sizes, int n_in,
                              void* d_out, int out_size, void* d_ws, size_t ws_size,
                              hipStream_t stream) {
    const float* x  = (const float*)d_in[0];
    const float* ew = (const float*)d_in[1];
    const int*   ei = (const int*)d_in[2];
    const float* w1 = (const float*)d_in[3];
    const float* w2 = (const float*)d_in[4];

    char* ws = (char*)d_ws;
    unsigned short* xbf  = (unsigned short*)(ws + OFF_XBF);
    unsigned short* w1T  = (unsigned short*)(ws + OFF_W1T);
    unsigned short* w2T  = (unsigned short*)(ws + OFF_W2T);
    unsigned short* Hb   = (unsigned short*)(ws + OFF_H);
    float*          outv = (float*)(ws + OFF_OUTV);
    int*            rowtok = (int*)(ws + OFF_RT);
    int*            hrof   = (int*)(ws + OFF_HROF);
    int*            te128  = (int*)(ws + OFF_TE128);
    int*            tr128  = (int*)(ws + OFF_TR128);
    int*            te64   = (int*)(ws + OFF_TE64);
    int*            tr64   = (int*)(ws + OFF_TR64);

    float* y   = (float*)d_out;
    float* buf = (float*)d_out + (size_t)NTOK * HS;

    // x -> bf16
    k_xcvt<<<(NTOK * HS / 4 + 255) / 256, 256, 0, stream>>>(x, xbf);
    // w1 [E][HS][FFN] -> w1T [E][FFN][HS] bf16 ; w2 [E][FFN][HS] -> w2T [E][HS][FFN] bf16
    k_transpose<<<dim3(FFN / 32, HS / 32, NE), dim3(32, 8), 0, stream>>>(w1, w1T, HS, FFN);
    k_transpose<<<dim3(HS / 32, FFN / 32, NE), dim3(32, 8), 0, stream>>>(w2, w2T, FFN, HS);
    // grouping
    k_setup<<<1, 256, 0, stream>>>(ei, rowtok, hrof, te128, tr128, te64, tr64);
    // GEMM1 + gelu -> H (bf16): M-tiles 128, N=FFN
    k_gemm<128, 128, HS, true><<<dim3(FFN / 128, MAXT128), 256, 0, stream>>>(
        xbf, w1T, Hb, rowtok, te128, tr128);
    // GEMM2 -> outv (f32): M-tiles 64, N=HS
    k_gemm<64, 128, FFN, false><<<dim3(HS / 128, MAXT64), 256, 0, stream>>>(
        Hb, w2T, outv, rowtok, te64, tr64);
    // combine into y and buffer (writes ALL buffer slots -> no memset needed)
    k_combine<<<NTOK * HS / 256, 256, 0, stream>>>(outv, ei, ew, hrof, y, buf);
}

// Round 4
// 86.727 us; speedup vs baseline: 1.3691x; 1.3691x over previous
//
#include <hip/hip_runtime.h>
#include <hip/hip_bf16.h>

// Problem constants
#define NTOK 2048
#define TOPK 2
#define HS   512
#define FFN  2048
#define NE   8
#define TASSIGN (NTOK*TOPK)   // 4096
#define PAD  5120             // 4096 + 8*128
#define MAXT128 40
#define MAXT64  72

typedef __attribute__((ext_vector_type(8))) short bf16x8;
typedef __attribute__((ext_vector_type(4))) float f32x4;

// ws layout (byte offsets); total ~67.15 MB
static const size_t OFF_XBF  = 0;            // [NTOK*HS] bf16
static const size_t OFF_W1T  = 2097152;      // [E][FFN][HS] bf16
static const size_t OFF_W2T  = 18874368;     // [E][HS][FFN] bf16
static const size_t OFF_H    = 35651584;     // [PAD][FFN] bf16
static const size_t OFF_OUTV = 56623104;     // [PAD][HS] f32
static const size_t OFF_RT   = 67108864;     // rowtok [PAD] int
static const size_t OFF_HROF = 67129344;     // hrof [TASSIGN] int
static const size_t OFF_TE128= 67145728;
static const size_t OFF_TR128= 67145888;
static const size_t OFF_TE64 = 67146048;
static const size_t OFF_TR64 = 67146336;

__device__ __forceinline__ unsigned short f2bf(float f) {
    union { __hip_bfloat16 h; unsigned short u; } v;
    v.h = __float2bfloat16(f);
    return v.u;
}

__device__ __forceinline__ int swz(int r, int byte_off) {
    return byte_off ^ ((r & 7) << 4);
}

#define GLOAD16(gsrc, ldst) \
    __builtin_amdgcn_global_load_lds((const __attribute__((address_space(1))) void*)(gsrc), \
                                     (__attribute__((address_space(3))) void*)(ldst), 16, 0, 0)

// ---- fused prep: setup (block 0) + x->bf16 (1024) + w1 transpose (8192) + w2 transpose (8192) ----
__device__ __forceinline__ void dev_transpose(const float* __restrict__ in,
                                              unsigned short* __restrict__ out,
                                              int R, int C, int e, int rb, int cb, int tid) {
    __shared__ unsigned short t[32][33];
    int tx = tid & 31, ty = tid >> 5;          // 32 x 8
    const float* ip = in + (size_t)e * R * C;
    unsigned short* op = out + (size_t)e * C * R;
#pragma unroll
    for (int i = 0; i < 4; i++) {
        int r = ty + i * 8;
        t[r][tx] = f2bf(ip[(size_t)(rb + r) * C + cb + tx]);
    }
    __syncthreads();
#pragma unroll
    for (int i = 0; i < 4; i++) {
        int c = ty + i * 8;
        op[(size_t)(cb + c) * R + rb + tx] = t[tx][c];
    }
}

__global__ __launch_bounds__(256) void k_prep(
        const float* __restrict__ x, const float* __restrict__ w1,
        const float* __restrict__ w2, const int* __restrict__ ei,
        unsigned short* __restrict__ xbf, unsigned short* __restrict__ w1T,
        unsigned short* __restrict__ w2T,
        int* __restrict__ rowtok, int* __restrict__ hrof,
        int* __restrict__ te128, int* __restrict__ tr128,
        int* __restrict__ te64, int* __restrict__ tr64) {
    int b = blockIdx.x;
    int tid = threadIdx.x;
    if (b == 0) {
        // setup: counting sort by expert, 128-padded segments, two tile tables
        __shared__ int cnt[NE], offpad[NE], cur[NE];
        for (int i = tid; i < PAD; i += 256) rowtok[i] = 0;   // pad rows -> token 0 (harmless)
        if (tid < NE) cnt[tid] = 0;
        __syncthreads();
        for (int a = tid; a < TASSIGN; a += 256) atomicAdd(&cnt[ei[a]], 1);
        __syncthreads();
        if (tid == 0) {
            int o = 0, t1 = 0, t2 = 0;
            for (int e = 0; e < NE; e++) {
                offpad[e] = o; cur[e] = 0;
                for (int r = 0; r < cnt[e]; r += 128) { te128[t1] = e; tr128[t1] = o + r; t1++; }
                for (int r = 0; r < cnt[e]; r += 64)  { te64[t2]  = e; tr64[t2]  = o + r; t2++; }
                o += (cnt[e] + 127) / 128 * 128;
            }
            for (; t1 < MAXT128; t1++) te128[t1] = -1;
            for (; t2 < MAXT64;  t2++) te64[t2]  = -1;
        }
        __syncthreads();
        for (int a = tid; a < TASSIGN; a += 256) {
            int e = ei[a];
            int r = atomicAdd(&cur[e], 1);
            int hr = offpad[e] + r;
            rowtok[hr] = a >> 1;       // token = assignment / TOPK
            hrof[a] = hr;
        }
    } else if (b < 1 + 1024) {
        int i = ((b - 1) * 256 + tid) * 4;
        float4 v = *(const float4*)(x + i);
        ushort4 o;
        o.x = f2bf(v.x); o.y = f2bf(v.y); o.z = f2bf(v.z); o.w = f2bf(v.w);
        *(ushort4*)(xbf + i) = o;
    } else if (b < 1 + 1024 + 8192) {
        // w1 [E][HS][FFN] -> w1T [E][FFN][HS]: R=HS, C=FFN
        int blk = b - 1025;
        int e = blk >> 10, rem = blk & 1023;
        dev_transpose(w1, w1T, HS, FFN, e, (rem >> 6) * 32, (rem & 63) * 32, tid);
    } else {
        // w2 [E][FFN][HS] -> w2T [E][HS][FFN]: R=FFN, C=HS
        int blk = b - 9217;
        int e = blk >> 10, rem = blk & 1023;
        dev_transpose(w2, w2T, FFN, HS, e, (rem >> 4) * 32, (rem & 15) * 32, tid);
    }
}

// ---- grouped GEMM: 2-phase double-buffered global_load_lds pipeline ----
// G1=true:  out = gelu(A_gathered @ B^T-layout), bf16 out
// G1=false: out = A @ B^T-layout, f32 out
template<int BM, int BN, int K, bool G1>
__global__ __launch_bounds__(256) void k_gemm(
        const unsigned short* __restrict__ A,
        const unsigned short* __restrict__ B,
        void* __restrict__ outp,
        const int* __restrict__ rowtok,
        const int* __restrict__ te, const int* __restrict__ tr, int N) {
    constexpr int MI = BM / 32, NJ = BN / 32;
    constexpr int PA = BM / 32, PB = BN / 32;       // gload sets of 256 lanes x 16B
    constexpr int ABYTES = BM * 64 * 2, BBYTES = BN * 64 * 2;
    constexpr int NSTEP = K / 64;
    static_assert(NSTEP % 2 == 0, "even steps");

    int mt = blockIdx.y;
    int e = te[mt];
    if (e < 0) return;
    int hr0 = tr[mt];
    int ct = blockIdx.x;

    __shared__ int4 ldsv[(2 * (ABYTES + BBYTES)) / 16];
    char* A0 = (char*)ldsv;
    char* A1 = A0 + ABYTES;
    char* B0 = A1 + ABYTES;
    char* B1 = B0 + BBYTES;

    int tid = threadIdx.x;
    int lane = tid & 63, wave = tid >> 6;
    int wm = wave >> 1, wn = wave & 1;

    // per-thread pre-swizzled global sources (chunk c8 of row r fetched from c8^(r&7))
    const char* asrc[PA];
    const char* bsrc[PB];
    int adoff[PA], bdoff[PB];
#pragma unroll
    for (int p = 0; p < PA; p++) {
        int idx = p * 256 + tid;
        int r = idx >> 3, c8 = idx & 7;
        int c8s = c8 ^ (r & 7);
        size_t row = G1 ? (size_t)rowtok[hr0 + r] : (size_t)(hr0 + r);
        asrc[p] = (const char*)(A + row * K) + c8s * 16;
        adoff[p] = (p * 256 + wave * 64) * 16;      // wave-uniform linear LDS dest
    }
#pragma unroll
    for (int p = 0; p < PB; p++) {
        int idx = p * 256 + tid;
        int r = idx >> 3, c8 = idx & 7;
        int c8s = c8 ^ (r & 7);
        bsrc[p] = (const char*)(B + ((size_t)e * N + (size_t)ct * BN + r) * K) + c8s * 16;
        bdoff[p] = (p * 256 + wave * 64) * 16;
    }

    f32x4 acc[MI][NJ] = {};

    auto stage = [&](char* Ad, char* Bd, int s) {
        int kb = s * 128;                            // 64 k-elems * 2B
#pragma unroll
        for (int p = 0; p < PA; p++) GLOAD16(asrc[p] + kb, Ad + adoff[p]);
#pragma unroll
        for (int p = 0; p < PB; p++) GLOAD16(bsrc[p] + kb, Bd + bdoff[p]);
    };
    auto compute = [&](const char* As, const char* Bs) {
#pragma unroll
        for (int kk = 0; kk < 64; kk += 32) {
            bf16x8 af[MI], bfv[NJ];
#pragma unroll
            for (int i = 0; i < MI; i++) {
                int ar = wm * (BM / 2) + i * 16 + (lane & 15);
                af[i] = *(const bf16x8*)(As + swz(ar, ar * 128 + kk * 2 + (lane >> 4) * 16));
            }
#pragma unroll
            for (int j = 0; j < NJ; j++) {
                int bc = wn * (BN / 2) + j * 16 + (lane & 15);
                bfv[j] = *(const bf16x8*)(Bs + swz(bc, bc * 128 + kk * 2 + (lane >> 4) * 16));
            }
#pragma unroll
            for (int i = 0; i < MI; i++)
#pragma unroll
                for (int j = 0; j < NJ; j++)
                    acc[i][j] = __builtin_amdgcn_mfma_f32_16x16x32_bf16(af[i], bfv[j], acc[i][j], 0, 0, 0);
        }
    };

    // prologue
    stage(A0, B0, 0);
    __syncthreads();                                 // buf0 ready
    // 2-phase pipeline: issue next-step loads before computing current step;
    // the single __syncthreads per step drains them only AFTER compute.
#pragma unroll 1
    for (int s = 0; s < NSTEP; s += 2) {
        if (s + 1 < NSTEP) stage(A1, B1, s + 1);
        compute(A0, B0);
        __syncthreads();
        if (s + 2 < NSTEP) stage(A0, B0, s + 2);
        compute(A1, B1);
        __syncthreads();
    }

    if constexpr (G1) {
        unsigned short* O = (unsigned short*)outp;
#pragma unroll
        for (int i = 0; i < MI; i++)
#pragma unroll
            for (int j = 0; j < NJ; j++)
#pragma unroll
                for (int q = 0; q < 4; q++) {
                    int row = hr0 + wm * (BM / 2) + i * 16 + (lane >> 4) * 4 + q;
                    int col = ct * BN + wn * (BN / 2) + j * 16 + (lane & 15);
                    float v = acc[i][j][q];
                    float g = 0.5f * v * (1.0f + erff(v * 0.70710678118f));
                    O[(size_t)row * N + col] = f2bf(g);
                }
    } else {
        float* O = (float*)outp;
#pragma unroll
        for (int i = 0; i < MI; i++)
#pragma unroll
            for (int j = 0; j < NJ; j++)
#pragma unroll
                for (int q = 0; q < 4; q++) {
                    int row = hr0 + wm * (BM / 2) + i * 16 + (lane >> 4) * 4 + q;
                    int col = ct * BN + wn * (BN / 2) + j * 16 + (lane & 15);
                    O[(size_t)row * N + col] = acc[i][j][q];
                }
    }
}

// ---- combine (float4): y[t] = w0*o0 + w1*o1 ; buffer[t][0..7] fully written ----
__global__ __launch_bounds__(256) void k_combine(
        const float4* __restrict__ outv, const int* __restrict__ ei,
        const float* __restrict__ ew, const int* __restrict__ hrof,
        float4* __restrict__ y, float4* __restrict__ buf) {
    int g = blockIdx.x * 256 + threadIdx.x;   // over NTOK*HS/4
    int t = g >> 7, c4 = g & 127;             // HS/4 = 128
    int a0 = 2 * t, a1 = a0 + 1;
    int h0 = hrof[a0], h1 = hrof[a1];
    float4 o0 = outv[(size_t)h0 * (HS / 4) + c4];
    float4 o1 = outv[(size_t)h1 * (HS / 4) + c4];
    float w0 = ew[a0], w1 = ew[a1];
    y[g] = make_float4(w0 * o0.x + w1 * o1.x, w0 * o0.y + w1 * o1.y,
                       w0 * o0.z + w1 * o1.z, w0 * o0.w + w1 * o1.w);
    int e0 = ei[a0], e1 = ei[a1];
    size_t base = (size_t)t * (NE * HS / 4) + c4;
#pragma unroll
    for (int e = 0; e < NE; e++) {
        float4 v = make_float4(0.f, 0.f, 0.f, 0.f);
        if (e == e0) { v.x += o0.x; v.y += o0.y; v.z += o0.z; v.w += o0.w; }
        if (e == e1) { v.x += o1.x; v.y += o1.y; v.z += o1.z; v.w += o1.w; }
        buf[base + (size_t)e * (HS / 4)] = v;
    }
}

extern "C" void kernel_launch(void* const* d_in, const int* in_sizes, int n_in,
                              void* d_out, int out_size, void* d_ws, size_t ws_size,
                              hipStream_t stream) {
    const float* x  = (const float*)d_in[0];
    const float* ew = (const float*)d_in[1];
    const int*   ei = (const int*)d_in[2];
    const float* w1 = (const float*)d_in[3];
    const float* w2 = (const float*)d_in[4];

    char* ws = (char*)d_ws;
    unsigned short* xbf  = (unsigned short*)(ws + OFF_XBF);
    unsigned short* w1T  = (unsigned short*)(ws + OFF_W1T);
    unsigned short* w2T  = (unsigned short*)(ws + OFF_W2T);
    unsigned short* Hb   = (unsigned short*)(ws + OFF_H);
    float*          outv = (float*)(ws + OFF_OUTV);
    int*            rowtok = (int*)(ws + OFF_RT);
    int*            hrof   = (int*)(ws + OFF_HROF);
    int*            te128  = (int*)(ws + OFF_TE128);
    int*            tr128  = (int*)(ws + OFF_TR128);
    int*            te64   = (int*)(ws + OFF_TE64);
    int*            tr64   = (int*)(ws + OFF_TR64);

    float* y   = (float*)d_out;
    float* buf = (float*)d_out + (size_t)NTOK * HS;

    // fused prep: setup + xcvt + both weight transposes (independent work, one launch)
    k_prep<<<1 + 1024 + 8192 + 8192, 256, 0, stream>>>(
        x, w1, w2, ei, xbf, w1T, w2T, rowtok, hrof, te128, tr128, te64, tr64);
    // GEMM1 + gelu -> H (bf16): 128x64 tiles, grid 32 x 40 = 1280 blocks
    k_gemm<128, 64, HS, true><<<dim3(FFN / 64, MAXT128), 256, 0, stream>>>(
        xbf, w1T, Hb, rowtok, te128, tr128, FFN);
    // GEMM2 -> outv (f32): 64x64 tiles, grid 8 x 72 = 576 blocks, K=2048
    k_gemm<64, 64, FFN, false><<<dim3(HS / 64, MAXT64), 256, 0, stream>>>(
        Hb, w2T, outv, rowtok, te64, tr64, HS);
    // combine into y and buffer (writes ALL buffer slots -> no memset needed)
    k_combine<<<NTOK * HS / 4 / 256, 256, 0, stream>>>(
        (const float4*)outv, ei, ew, hrof, (float4*)y, (float4*)buf);
}